// Round 4
// baseline (18.649 us; speedup 1.0000x reference)
//
#include <hip/hip_runtime.h>
#include <hip/hip_bf16.h>

typedef __attribute__((ext_vector_type(4))) float f32x4;
typedef __attribute__((ext_vector_type(2))) double f64x2;
typedef __attribute__((ext_vector_type(8))) short short8;

#define NA 1024
#define NB 1024
#define KF 256
#define DIM 128

// ---------------- Phase 1: fk = X @ feats^T -> P (relu, bf16), M (mask<=0, bf16) ----
// Block = 16 rows x 128 cols. Grid = 128 row-blocks x 2 col-blocks = 256 (1/CU).
// Wave w owns rows row0+4w..+3 (wave-uniform) -> X comes from global via uniform
// (SGPR) loads + v_cvt_f64_f32; ZERO LDS traffic for X. Only feats slice lives in
// LDS (f64, pitch 130 -> conflict-free strided ds_read_b128).
// FIX vs last round: stage ALL 4096 f32x4 chunks of the 128-row feats slice
// (16 per thread, not 8 — rows 64..127 were uninitialized garbage).
#define RB 16
#define CBLK 128
#define FP 130

__global__ __launch_bounds__(256) void proj_kernel(
    const float* __restrict__ a, const float* __restrict__ b,
    const float* __restrict__ feats,
    __hip_bfloat16* __restrict__ P, __hip_bfloat16* __restrict__ M)
{
    __shared__ double Fd[CBLK][FP];   // 133,120 B

    const int t = threadIdx.x;
    const int rowBlk = blockIdx.x >> 1;
    const int colBlk = blockIdx.x & 1;
    const int row0 = rowBlk * RB;          // row in concatenated [a;b]
    const int col0 = colBlk * CBLK;

    const bool isA = row0 < NA;
    const float* __restrict__ src = isA ? a : b;
    const int r0 = isA ? row0 : row0 - NA;

    // stage feats slice as f64: 128 rows x 32 f32x4 chunks = 4096 chunks, 16/thread
#pragma unroll
    for (int i = 0; i < 16; ++i) {
        int idx = t + i * 256;
        int c = idx >> 5, q = idx & 31;
        f32x4 v = ((const f32x4*)(feats + (size_t)(col0 + c) * DIM))[q];
        *(f64x2*)&Fd[c][q * 4] = (f64x2){(double)v[0], (double)v[1]};
        *(f64x2*)&Fd[c][q * 4 + 2] = (f64x2){(double)v[2], (double)v[3]};
    }
    __syncthreads();

    const int wid = t >> 6;
    const int l = t & 63;

    // wave-uniform X row base -> scalar loads
    const float* __restrict__ xp =
        src + (size_t)__builtin_amdgcn_readfirstlane(r0 + wid * 4) * DIM;

    double acc[4][2] = {{0.0, 0.0}, {0.0, 0.0}, {0.0, 0.0}, {0.0, 0.0}};

    f32x4 xc[4];
#pragma unroll
    for (int r = 0; r < 4; ++r) xc[r] = *(const f32x4*)(xp + r * DIM);

#pragma unroll 2
    for (int d = 0; d < DIM; d += 4) {
        f32x4 xn[4];
        if (d + 4 < DIM) {
#pragma unroll
            for (int r = 0; r < 4; ++r) xn[r] = *(const f32x4*)(xp + r * DIM + d + 4);
        }
        f64x2 f0[2], f1[2];
        f0[0] = *(const f64x2*)&Fd[l][d];
        f0[1] = *(const f64x2*)&Fd[l][d + 2];
        f1[0] = *(const f64x2*)&Fd[l + 64][d];
        f1[1] = *(const f64x2*)&Fd[l + 64][d + 2];
#pragma unroll
        for (int r = 0; r < 4; ++r) {
            double x0 = (double)xc[r][0], x1 = (double)xc[r][1];
            double x2 = (double)xc[r][2], x3 = (double)xc[r][3];
            acc[r][0] = fma(x0, f0[0][0], acc[r][0]);
            acc[r][0] = fma(x1, f0[0][1], acc[r][0]);
            acc[r][0] = fma(x2, f0[1][0], acc[r][0]);
            acc[r][0] = fma(x3, f0[1][1], acc[r][0]);
            acc[r][1] = fma(x0, f1[0][0], acc[r][1]);
            acc[r][1] = fma(x1, f1[0][1], acc[r][1]);
            acc[r][1] = fma(x2, f1[1][0], acc[r][1]);
            acc[r][1] = fma(x3, f1[1][1], acc[r][1]);
        }
#pragma unroll
        for (int r = 0; r < 4; ++r) xc[r] = xn[r];
    }

    if (isA) {
#pragma unroll
        for (int r = 0; r < 4; ++r) {
            size_t grow = (size_t)(r0 + wid * 4 + r) * KF;
            float v0 = (acc[r][0] > 0.0) ? (float)acc[r][0] : 0.0f;
            float v1 = (acc[r][1] > 0.0) ? (float)acc[r][1] : 0.0f;
            P[grow + col0 + l] = __float2bfloat16(v0);
            P[grow + col0 + l + 64] = __float2bfloat16(v1);
        }
    } else {
#pragma unroll
        for (int r = 0; r < 4; ++r) {
            size_t grow = (size_t)(r0 + wid * 4 + r) * KF;
            float v0 = (acc[r][0] <= 0.0) ? 1.0f : 0.0f;
            float v1 = (acc[r][1] <= 0.0) ? 1.0f : 0.0f;
            M[grow + col0 + l] = __float2bfloat16(v0);
            M[grow + col0 + l + 64] = __float2bfloat16(v1);
        }
    }
}

// ---------------- Phase 2: out = P @ M^T, bf16 MFMA, f32 accumulate (unchanged) ------
__global__ __launch_bounds__(256) void gemm_kernel(
    const __hip_bfloat16* __restrict__ P, const __hip_bfloat16* __restrict__ M,
    float* __restrict__ out)
{
    __shared__ short LA[64][264];
    __shared__ short LB[64][264];
    const int t = threadIdx.x;
    const int row0 = blockIdx.y * 64;
    const int col0 = blockIdx.x * 64;
    const short* Pa = (const short*)P;
    const short* Mb = (const short*)M;

#pragma unroll
    for (int i = 0; i < 8; ++i) {
        int c = t + i * 256;
        int row = c >> 5;
        int c8 = (c & 31) << 3;
        *(short8*)&LA[row][c8] = *(const short8*)(Pa + (size_t)(row0 + row) * KF + c8);
        *(short8*)&LB[row][c8] = *(const short8*)(Mb + (size_t)(col0 + row) * KF + c8);
    }
    __syncthreads();

    const int lane = t & 63;
    const int wid = t >> 6;
    const int wr = (wid >> 1) * 32;
    const int wc = (wid & 1) * 32;
    const int fr = lane & 15;
    const int fq = lane >> 4;

    f32x4 acc[2][2];
#pragma unroll
    for (int m = 0; m < 2; ++m)
#pragma unroll
        for (int n = 0; n < 2; ++n)
            acc[m][n] = (f32x4){0.f, 0.f, 0.f, 0.f};

#pragma unroll
    for (int kk = 0; kk < KF / 32; ++kk) {
        const int kb = kk * 32 + fq * 8;
        short8 a0 = *(const short8*)&LA[wr + fr][kb];
        short8 a1 = *(const short8*)&LA[wr + 16 + fr][kb];
        short8 b0 = *(const short8*)&LB[wc + fr][kb];
        short8 b1 = *(const short8*)&LB[wc + 16 + fr][kb];
        acc[0][0] = __builtin_amdgcn_mfma_f32_16x16x32_bf16(a0, b0, acc[0][0], 0, 0, 0);
        acc[0][1] = __builtin_amdgcn_mfma_f32_16x16x32_bf16(a0, b1, acc[0][1], 0, 0, 0);
        acc[1][0] = __builtin_amdgcn_mfma_f32_16x16x32_bf16(a1, b0, acc[1][0], 0, 0, 0);
        acc[1][1] = __builtin_amdgcn_mfma_f32_16x16x32_bf16(a1, b1, acc[1][1], 0, 0, 0);
    }

#pragma unroll
    for (int m = 0; m < 2; ++m)
#pragma unroll
        for (int n = 0; n < 2; ++n)
#pragma unroll
            for (int r = 0; r < 4; ++r) {
                int row = row0 + wr + m * 16 + fq * 4 + r;
                int col = col0 + wc + n * 16 + fr;
                out[(size_t)row * NB + col] = acc[m][n][r];
            }
}

extern "C" void kernel_launch(void* const* d_in, const int* in_sizes, int n_in,
                              void* d_out, int out_size, void* d_ws, size_t ws_size,
                              hipStream_t stream) {
    const float* a = (const float*)d_in[0];
    const float* b = (const float*)d_in[1];
    const float* feats = (const float*)d_in[2];
    float* out = (float*)d_out;
    __hip_bfloat16* P = (__hip_bfloat16*)d_ws;
    __hip_bfloat16* M = P + (size_t)NA * KF;

    proj_kernel<<<dim3(256), dim3(256), 0, stream>>>(a, b, feats, P, M);
    gemm_kernel<<<dim3(NB / 64, NA / 64), dim3(256), 0, stream>>>(P, M, out);
}

// Round 6
// 14.306 us; speedup vs baseline: 1.3036x; 1.3036x over previous
//
#include <hip/hip_runtime.h>
#include <hip/hip_bf16.h>

typedef __attribute__((ext_vector_type(4))) float f32x4;
typedef __attribute__((ext_vector_type(4))) double f64x4;
typedef __attribute__((ext_vector_type(8))) short short8;

#define NA 1024
#define NB 1024
#define KF 256
#define DIM 128

// ---------------- Phase 1: fk = X @ feats^T -> P (relu, bf16), M (mask<=0, bf16) ----
// f64 MFMA (v_mfma_f64_16x16x4f64) does the 67M f64 mul-adds on the matrix pipe.
// R5 failed because the f64 C/D register->row mapping differs from the bf16 16x16
// convention (f64 was never in the verified dtype-independence set). This version
// is LAYOUT-AGNOSTIC: a 2-MFMA probe makes the HW report each acc slot's (m,n):
//   probe after MFMA1 (A[m][k]=m, B=1):      += 4*m
//   probe after MFMA2 (A=1, B[k][n]=64*n):   += 256*n
// so probe[r] = 4m + 256n exactly; decode m=(code>>2)&15, n=code>>8 and write
// acc[r] there. Correct under ANY D permutation.
// A/B mappings are cardinality-forced: A: m=l&15,k=l>>4; B: n=l&15,k=l>>4.
#define PRB 64
#define PCB 16
#define PP 132

__global__ __launch_bounds__(256) void proj_kernel(
    const float* __restrict__ a, const float* __restrict__ b,
    const float* __restrict__ feats,
    __hip_bfloat16* __restrict__ P, __hip_bfloat16* __restrict__ M)
{
    __shared__ float Xs[PRB][PP];   // 33,792 B
    __shared__ float Fs[PCB][PP];   //  8,448 B

    const int t = threadIdx.x;
    const int rowBlk = blockIdx.x >> 4;   // 0..31
    const int colBlk = blockIdx.x & 15;   // 0..15
    const int row0 = rowBlk * PRB;        // concat row
    const int col0 = colBlk * PCB;

    const bool isA = row0 < NA;
    const float* __restrict__ src = isA ? a : b;
    const int r0 = isA ? row0 : row0 - NA;

    // stage X: 64 rows x 32 f32x4 chunks = 2048, 8/thread (coalesced)
#pragma unroll
    for (int i = 0; i < 8; ++i) {
        int idx = t + i * 256;
        int r = idx >> 5, c4 = idx & 31;
        *(f32x4*)&Xs[r][c4 * 4] =
            *(const f32x4*)(src + (size_t)(r0 + r) * DIM + c4 * 4);
    }
    // stage F: 16 rows x 32 chunks = 512, 2/thread
#pragma unroll
    for (int i = 0; i < 2; ++i) {
        int idx = t + i * 256;
        int r = idx >> 5, c4 = idx & 31;
        *(f32x4*)&Fs[r][c4 * 4] =
            *(const f32x4*)(feats + (size_t)(col0 + r) * DIM + c4 * 4);
    }
    __syncthreads();

    const int l = t & 63;
    const int w = t >> 6;
    const int fr = l & 15;   // A-row / B-col index supplied by this lane
    const int fq = l >> 4;   // k index 0..3

    // ---- layout probe: probe[r] = 4*m + 256*n for this lane's acc slot r ----
    f64x4 probe = {0.0, 0.0, 0.0, 0.0};
    probe = __builtin_amdgcn_mfma_f64_16x16x4f64((double)fr, 1.0, probe, 0, 0, 0);
    probe = __builtin_amdgcn_mfma_f64_16x16x4f64(1.0, 64.0 * (double)fr, probe, 0, 0, 0);

    const float* __restrict__ xrow = &Xs[w * 16 + fr][fq];
    const float* __restrict__ frow = &Fs[fr][fq];

    f64x4 acc0 = {0.0, 0.0, 0.0, 0.0};
    f64x4 acc1 = {0.0, 0.0, 0.0, 0.0};

#pragma unroll
    for (int s = 0; s < 32; s += 2) {
        double a0 = (double)xrow[s * 4];
        double b0 = (double)frow[s * 4];
        acc0 = __builtin_amdgcn_mfma_f64_16x16x4f64(a0, b0, acc0, 0, 0, 0);
        double a1 = (double)xrow[s * 4 + 4];
        double b1 = (double)frow[s * 4 + 4];
        acc1 = __builtin_amdgcn_mfma_f64_16x16x4f64(a1, b1, acc1, 0, 0, 0);
    }

    if (isA) {
#pragma unroll
        for (int r = 0; r < 4; ++r) {
            int code = (int)probe[r];
            int m = (code >> 2) & 15;
            int n = code >> 8;
            double v = acc0[r] + acc1[r];
            float vr = (v > 0.0) ? (float)v : 0.0f;
            P[(size_t)(r0 + w * 16 + m) * KF + col0 + n] = __float2bfloat16(vr);
        }
    } else {
#pragma unroll
        for (int r = 0; r < 4; ++r) {
            int code = (int)probe[r];
            int m = (code >> 2) & 15;
            int n = code >> 8;
            double v = acc0[r] + acc1[r];
            float vr = (v <= 0.0) ? 1.0f : 0.0f;
            M[(size_t)(r0 + w * 16 + m) * KF + col0 + n] = __float2bfloat16(vr);
        }
    }
}

// ---------------- Phase 2: out = P @ M^T, bf16 MFMA, f32 accumulate (unchanged) ------
__global__ __launch_bounds__(256) void gemm_kernel(
    const __hip_bfloat16* __restrict__ P, const __hip_bfloat16* __restrict__ M,
    float* __restrict__ out)
{
    __shared__ short LA[64][264];
    __shared__ short LB[64][264];
    const int t = threadIdx.x;
    const int row0 = blockIdx.y * 64;
    const int col0 = blockIdx.x * 64;
    const short* Pa = (const short*)P;
    const short* Mb = (const short*)M;

#pragma unroll
    for (int i = 0; i < 8; ++i) {
        int c = t + i * 256;
        int row = c >> 5;
        int c8 = (c & 31) << 3;
        *(short8*)&LA[row][c8] = *(const short8*)(Pa + (size_t)(row0 + row) * KF + c8);
        *(short8*)&LB[row][c8] = *(const short8*)(Mb + (size_t)(col0 + row) * KF + c8);
    }
    __syncthreads();

    const int lane = t & 63;
    const int wid = t >> 6;
    const int wr = (wid >> 1) * 32;
    const int wc = (wid & 1) * 32;
    const int fr = lane & 15;
    const int fq = lane >> 4;

    f32x4 acc[2][2];
#pragma unroll
    for (int m = 0; m < 2; ++m)
#pragma unroll
        for (int n = 0; n < 2; ++n)
            acc[m][n] = (f32x4){0.f, 0.f, 0.f, 0.f};

#pragma unroll
    for (int kk = 0; kk < KF / 32; ++kk) {
        const int kb = kk * 32 + fq * 8;
        short8 a0 = *(const short8*)&LA[wr + fr][kb];
        short8 a1 = *(const short8*)&LA[wr + 16 + fr][kb];
        short8 b0 = *(const short8*)&LB[wc + fr][kb];
        short8 b1 = *(const short8*)&LB[wc + 16 + fr][kb];
        acc[0][0] = __builtin_amdgcn_mfma_f32_16x16x32_bf16(a0, b0, acc[0][0], 0, 0, 0);
        acc[0][1] = __builtin_amdgcn_mfma_f32_16x16x32_bf16(a0, b1, acc[0][1], 0, 0, 0);
        acc[1][0] = __builtin_amdgcn_mfma_f32_16x16x32_bf16(a1, b0, acc[1][0], 0, 0, 0);
        acc[1][1] = __builtin_amdgcn_mfma_f32_16x16x32_bf16(a1, b1, acc[1][1], 0, 0, 0);
    }

#pragma unroll
    for (int m = 0; m < 2; ++m)
#pragma unroll
        for (int n = 0; n < 2; ++n)
#pragma unroll
            for (int r = 0; r < 4; ++r) {
                int row = row0 + wr + m * 16 + fq * 4 + r;
                int col = col0 + wc + n * 16 + fr;
                out[(size_t)row * NB + col] = acc[m][n][r];
            }
}

extern "C" void kernel_launch(void* const* d_in, const int* in_sizes, int n_in,
                              void* d_out, int out_size, void* d_ws, size_t ws_size,
                              hipStream_t stream) {
    const float* a = (const float*)d_in[0];
    const float* b = (const float*)d_in[1];
    const float* feats = (const float*)d_in[2];
    float* out = (float*)d_out;
    __hip_bfloat16* P = (__hip_bfloat16*)d_ws;
    __hip_bfloat16* M = P + (size_t)NA * KF;

    proj_kernel<<<dim3(512), dim3(256), 0, stream>>>(a, b, feats, P, M);
    gemm_kernel<<<dim3(NB / 64, NA / 64), dim3(256), 0, stream>>>(P, M, out);
}